// Round 6
// baseline (18.019 us; speedup 1.0000x reference)
//
#include <hip/hip_runtime.h>
#include <hip/hip_bf16.h>

// Node dimension is degenerate: cur starts as broadcast(z) (node-constant),
// contents node-constant, gather of node-constant is node-constant. Output
// [64,65536,1] = one scalar per batch broadcast over 65536 nodes.
//
// Round-5 lesson: fused kernel = 14.0us total, ~6us kernel + ~8us replay
// overhead. Fat: 150+ VGPR prefetch and 11 barriers for tiny tail layers.
// This round: prefetch only W0 (36 regs); 3 barriers total; after the L0
// partial, every wave finishes L0-reduce + L1..L4 redundantly in-register
// via __shfl broadcasts (lane-masked addressing, no divergence, no OOB) +
// uniform-addr LDS broadcasts for contents. No barrier before the fill.

template <int F>
__device__ __forceinline__ float LDF(const void* p, int i) {
    if (F) return ((const float*)p)[i];
    return __bfloat162float(((const __hip_bfloat16*)p)[i]);
}
template <int I>
__device__ __forceinline__ int IDXT(const void* p, int i) {
    if (I) return (int)((const long long*)p)[i];
    return ((const int*)p)[i];
}

struct ChainArgs {
    const void *z, *studies, *tasks, *contrasts;
    const void *emb_s_v, *emb_s_g, *emb_t_v, *emb_t_g, *emb_c_v, *emb_c_g;
    const void *fc_w[5], *fc_b[5];
    const void *W[5], *bias[5];
};

struct Smem {
    float cat3[48];      // [se | te | ce]
    float contents[80];  // [16..32)=c1 [32..48)=c2 [48..64)=c3 [64..80)=c4
    float xa[144];       // [z | c0]
    float partial[256];  // L0 split-K partials
};

__device__ __forceinline__ float lrelu(float a) { return fmaxf(a, 0.2f * a); }

template <int F, int I>
__device__ __forceinline__ void chain_fill(
    const ChainArgs& a, float* __restrict__ out, int b, int slice, int t, Smem& sm)
{
    const int lane = t & 63;
    const int q    = t >> 6;   // wave id = L0 k-chunk

    // ---- prefetch W0 only (the one big operand): 36 regs ----
    float w0r[36];
    #pragma unroll
    for (int k = 0; k < 36; ++k) w0r[k] = LDF<F>(a.W[0], (q * 36 + k) * 64 + lane);

    // ================= E: embeddings + z staging =================
    if (t < 48) {
        const int g = t >> 4, j = t & 15;
        int row;
        if (g == 0)      row = IDXT<I>(a.studies, b);
        else if (g == 1) row = IDXT<I>(a.tasks, b);
        else             row = IDXT<I>(a.contrasts, b);
        const void* v  = (g == 0) ? a.emb_s_v : (g == 1) ? a.emb_t_v : a.emb_c_v;
        const void* gp = (g == 0) ? a.emb_s_g : (g == 1) ? a.emb_t_g : a.emb_c_g;
        float gain = LDF<F>(gp, row);
        float vr[16];
        #pragma unroll
        for (int k = 0; k < 16; ++k) vr[k] = LDF<F>(v, row * 16 + k);
        float n2 = 0.f;
        #pragma unroll
        for (int k = 0; k < 16; ++k) n2 += vr[k] * vr[k];
        sm.cat3[t] = gain * vr[j] * rsqrtf(n2);
    } else if (t < 176) {
        sm.xa[t - 48] = LDF<F>(a.z, b * 128 + (t - 48));
    }
    __syncthreads();

    // ================= C: content FCs =================
    if (t < 16) {                       // c0 -> straight into xa[128..144)
        float acc = LDF<F>(a.fc_b[0], t);
        #pragma unroll
        for (int k = 0; k < 16; ++k) acc += sm.cat3[k] * LDF<F>(a.fc_w[0], k * 16 + t);
        sm.xa[128 + t] = acc;
    } else if (t < 32) {                // c1
        const int j = t & 15;
        float acc = LDF<F>(a.fc_b[1], j);
        #pragma unroll
        for (int k = 0; k < 32; ++k) acc += sm.cat3[k] * LDF<F>(a.fc_w[1], k * 16 + j);
        sm.contents[16 + j] = acc;
    } else if (t < 80) {                // c2, c3, c4
        const int i = t >> 4, j = t & 15;
        const void* fw = a.fc_w[i];
        float acc = LDF<F>(a.fc_b[i], j);
        #pragma unroll
        for (int k = 0; k < 48; ++k) acc += sm.cat3[k] * LDF<F>(fw, k * 16 + j);
        sm.contents[i * 16 + j] = acc;
    }
    __syncthreads();

    // ================= L0 partial: 144 -> 64, 4-way split-K =================
    {
        float acc = 0.f;
        #pragma unroll
        for (int k = 0; k < 36; ++k) acc += sm.xa[q * 36 + k] * w0r[k];
        sm.partial[t] = acc;
    }
    __syncthreads();

    // ======= all-wave redundant tail: L0 reduce + L1..L4, zero barriers =======
    // L0 reduce: lane j holds h0_j
    float h0 = lrelu(LDF<F>(a.bias[0], lane)
                     + sm.partial[lane] + sm.partial[64 + lane]
                     + sm.partial[128 + lane] + sm.partial[192 + lane]);

    // L1: 80 -> 32 (h0[64] | c1[16]); lanes duplicated mod 32
    float h1;
    {
        const int j = lane & 31;
        float acc = LDF<F>(a.bias[1], j);
        #pragma unroll
        for (int k = 0; k < 64; ++k) acc += __shfl(h0, k) * LDF<F>(a.W[1], k * 32 + j);
        #pragma unroll
        for (int k = 0; k < 16; ++k) acc += sm.contents[16 + k] * LDF<F>(a.W[1], (64 + k) * 32 + j);
        h1 = lrelu(acc);
    }

    // L2: 48 -> 16 (h1[32] | c2[16]); lanes duplicated mod 16
    float h2;
    {
        const int j = lane & 15;
        float acc = LDF<F>(a.bias[2], j);
        #pragma unroll
        for (int k = 0; k < 32; ++k) acc += __shfl(h1, k) * LDF<F>(a.W[2], k * 16 + j);
        #pragma unroll
        for (int k = 0; k < 16; ++k) acc += sm.contents[32 + k] * LDF<F>(a.W[2], (32 + k) * 16 + j);
        h2 = lrelu(acc);
    }

    // L3: 32 -> 8 (h2[16] | c3[16]); lanes duplicated mod 8
    float h3;
    {
        const int j = lane & 7;
        float acc = LDF<F>(a.bias[3], j);
        #pragma unroll
        for (int k = 0; k < 16; ++k) acc += __shfl(h2, k) * LDF<F>(a.W[3], k * 8 + j);
        #pragma unroll
        for (int k = 0; k < 16; ++k) acc += sm.contents[48 + k] * LDF<F>(a.W[3], (16 + k) * 8 + j);
        h3 = lrelu(acc);
    }

    // L4: 24 -> 1 (h3[8] | c4[16]); every lane computes the scalar
    float res;
    {
        float acc = LDF<F>(a.bias[4], 0);
        #pragma unroll
        for (int k = 0; k < 8; ++k)  acc += __shfl(h3, k) * LDF<F>(a.W[4], k);
        #pragma unroll
        for (int k = 0; k < 16; ++k) acc += sm.contents[64 + k] * LDF<F>(a.W[4], 8 + k);
        res = acc;
    }

    // ================= fill this block's 32 KB slice =================
    const float4 val = make_float4(res, res, res, res);
    float4* __restrict__ o = reinterpret_cast<float4*>(out) + (size_t)b * 16384 + slice * 2048;
    #pragma unroll
    for (int k = 0; k < 8; ++k) o[k * 256 + t] = val;
}

__global__ __launch_bounds__(256) void fgl_fused_kernel(ChainArgs a, float* __restrict__ out)
{
    const int b = blockIdx.x >> 3;       // batch
    const int slice = blockIdx.x & 7;    // 1/8 of the batch's output
    const int t = threadIdx.x;

    __shared__ Smem sm;
    __shared__ int FI_s;

    // dtype sniff (validated rounds 3-5):
    //  F: any of z's first 32 words with bf16-exponent(low half) >= 0x89 -> f32.
    //  I: contrasts values 0..199; int64 => 32 high words all zero.
    if (t < 64) {
        bool fcond = false, icond = false;
        if (t < 32) {
            unsigned int wz = ((const unsigned int*)a.z)[t];
            fcond = ((wz >> 7) & 0xFF) >= 0x89;
            icond = (((const unsigned int*)a.contrasts)[2 * t + 1] != 0u);
        }
        unsigned long long bf = __ballot(fcond);
        unsigned long long bi = __ballot(icond);
        if (t == 0) FI_s = (bf ? 1 : 0) | ((bi == 0ull) ? 2 : 0);
    }
    __syncthreads();
    const int FI = FI_s;

    if (FI == 1)      chain_fill<1, 0>(a, out, b >> 0, blockIdx.x & 7, t, sm);
    else if (FI == 3) chain_fill<1, 1>(a, out, b, blockIdx.x & 7, t, sm);
    else if (FI == 0) chain_fill<0, 0>(a, out, b, blockIdx.x & 7, t, sm);
    else              chain_fill<0, 1>(a, out, b, blockIdx.x & 7, t, sm);
    (void)slice;
}

extern "C" void kernel_launch(void* const* d_in, const int* in_sizes, int n_in,
                              void* d_out, int out_size, void* d_ws, size_t ws_size,
                              hipStream_t stream) {
    ChainArgs a;
    a.z = d_in[0];
    a.studies = d_in[1];
    a.tasks = d_in[2];
    a.contrasts = d_in[3];
    // d_in[4..8] = p0..p4 — mathematically irrelevant
    a.emb_s_v = d_in[9];  a.emb_s_g = d_in[10];
    a.emb_t_v = d_in[11]; a.emb_t_g = d_in[12];
    a.emb_c_v = d_in[13]; a.emb_c_g = d_in[14];
    for (int i = 0; i < 5; ++i) {
        a.fc_w[i] = d_in[15 + 2 * i];
        a.fc_b[i] = d_in[16 + 2 * i];
        a.W[i]    = d_in[25 + 2 * i];
        a.bias[i] = d_in[26 + 2 * i];
    }
    // 512 blocks: 64 batches x 8 slices; each block = chain + 32 KB fill.
    fgl_fused_kernel<<<512, 256, 0, stream>>>(a, (float*)d_out);
}

// Round 7
// 14.055 us; speedup vs baseline: 1.2820x; 1.2820x over previous
//
#include <hip/hip_runtime.h>
#include <hip/hip_bf16.h>

// Node dimension is degenerate: cur starts as broadcast(z) (node-constant),
// contents node-constant, gather of node-constant is node-constant. Output
// [64,65536,1] = one scalar per batch broadcast over 65536 nodes.
//
// Round-6 lesson: shfl-tail multiplied per-thread weight loads (24M L2 loads,
// ~96 MB L2 traffic) -> +4us. Split-K ladder amortizes weight traffic 256x.
// This round: R5 (best, 14.0us) + two trims with ZERO extra vector loads:
//  - L4 computed redundantly per-thread from thread-invariant addresses
//    (compiler uses scalar loads) + uniform LDS broadcasts: -2 barriers,
//    no final sync before fill.
//  - c4 staging removed (read contents[] directly).

template <int F>
__device__ __forceinline__ float LDF(const void* p, int i) {
    if (F) return ((const float*)p)[i];
    return __bfloat162float(((const __hip_bfloat16*)p)[i]);
}
template <int I>
__device__ __forceinline__ int IDXT(const void* p, int i) {
    if (I) return (int)((const long long*)p)[i];
    return ((const int*)p)[i];
}

struct ChainArgs {
    const void *z, *studies, *tasks, *contrasts;
    const void *emb_s_v, *emb_s_g, *emb_t_v, *emb_t_g, *emb_c_v, *emb_c_g;
    const void *fc_w[5], *fc_b[5];
    const void *W[5], *bias[5];
};

struct Smem {
    float cat3[48];      // [se | te | ce]
    float contents[80];  // [16..32)=c1 [32..48)=c2 [48..64)=c3 [64..80)=c4
    float xa[144];       // [z | c0] then reused for h1|c2, h3
    float xb[96];        // h0|c1 then h2|c3
    float partial[256];  // split-K partials
};

__device__ __forceinline__ float lrelu(float a) { return fmaxf(a, 0.2f * a); }

template <int F, int I>
__device__ __forceinline__ void chain_fill(
    const ChainArgs& a, float* __restrict__ out, int b, int slice, int t, Smem& sm)
{
    // ================= register prefetch (R5-proven) =================
    float zr = 0.f;
    if (t >= 48 && t < 176) zr = LDF<F>(a.z, b * 128 + (t - 48));

    int row = 0;
    if (t < 48) {
        const int g = t >> 4;
        if (g == 0)      row = IDXT<I>(a.studies, b);
        else if (g == 1) row = IDXT<I>(a.tasks, b);
        else             row = IDXT<I>(a.contrasts, b);
    }

    float w0r[36];
    {   const int j = t & 63, q = t >> 6;
        #pragma unroll
        for (int k = 0; k < 36; ++k) w0r[k] = LDF<F>(a.W[0], (q * 36 + k) * 64 + j);
    }
    float w1r[10];
    {   const int j = t & 31, q = t >> 5;
        #pragma unroll
        for (int k = 0; k < 10; ++k) w1r[k] = LDF<F>(a.W[1], (q * 10 + k) * 32 + j);
    }
    float w2r[3];
    {   const int j = t & 15, q = t >> 4;
        #pragma unroll
        for (int k = 0; k < 3; ++k) w2r[k] = LDF<F>(a.W[2], (q * 3 + k) * 16 + j);
    }
    float w3r;
    {   const int j = t & 7, q = t >> 3;
        w3r = LDF<F>(a.W[3], q * 8 + j);
    }
    float b0r = (t < 64) ? LDF<F>(a.bias[0], t) : 0.f;
    float b1r = (t < 32) ? LDF<F>(a.bias[1], t) : 0.f;
    float b2r = (t < 16) ? LDF<F>(a.bias[2], t) : 0.f;
    float b3r = (t < 8)  ? LDF<F>(a.bias[3], t) : 0.f;

    float fcw[48];
    float fcb = 0.f;
    if (t < 16) {
        fcb = LDF<F>(a.fc_b[0], t);
        #pragma unroll
        for (int k = 0; k < 16; ++k) fcw[k] = LDF<F>(a.fc_w[0], k * 16 + t);
    } else if (t < 32) {
        const int j = t & 15;
        fcb = LDF<F>(a.fc_b[1], j);
        #pragma unroll
        for (int k = 0; k < 32; ++k) fcw[k] = LDF<F>(a.fc_w[1], k * 16 + j);
    } else if (t < 48) {
        const int j = t & 15;
        fcb = LDF<F>(a.fc_b[2], j);
        #pragma unroll
        for (int k = 0; k < 48; ++k) fcw[k] = LDF<F>(a.fc_w[2], k * 16 + j);
    } else if (t < 64) {
        const int j = t & 15;
        fcb = LDF<F>(a.fc_b[3], j);
        #pragma unroll
        for (int k = 0; k < 48; ++k) fcw[k] = LDF<F>(a.fc_w[3], k * 16 + j);
    } else if (t < 80) {
        const int j = t & 15;
        fcb = LDF<F>(a.fc_b[4], j);
        #pragma unroll
        for (int k = 0; k < 48; ++k) fcw[k] = LDF<F>(a.fc_w[4], k * 16 + j);
    }

    // ================= E: embeddings + z staging =================
    if (t < 48) {
        const int g = t >> 4, j = t & 15;
        const void* v  = (g == 0) ? a.emb_s_v : (g == 1) ? a.emb_t_v : a.emb_c_v;
        const void* gp = (g == 0) ? a.emb_s_g : (g == 1) ? a.emb_t_g : a.emb_c_g;
        float gain = LDF<F>(gp, row);
        float vr[16];
        #pragma unroll
        for (int k = 0; k < 16; ++k) vr[k] = LDF<F>(v, row * 16 + k);
        float n2 = 0.f;
        #pragma unroll
        for (int k = 0; k < 16; ++k) n2 += vr[k] * vr[k];
        sm.cat3[t] = gain * vr[j] * rsqrtf(n2);
    } else if (t < 176) {
        sm.xa[t - 48] = zr;
    }
    __syncthreads();

    // ================= C: content FCs =================
    if (t < 16) {                       // c0 -> straight into xa[128..144)
        float acc = fcb;
        #pragma unroll
        for (int k = 0; k < 16; ++k) acc += sm.cat3[k] * fcw[k];
        sm.xa[128 + t] = acc;
    } else if (t < 32) {                // c1
        const int j = t & 15;
        float acc = fcb;
        #pragma unroll
        for (int k = 0; k < 32; ++k) acc += sm.cat3[k] * fcw[k];
        sm.contents[16 + j] = acc;
    } else if (t < 80) {                // c2, c3, c4
        const int i = t >> 4, j = t & 15;
        float acc = fcb;
        #pragma unroll
        for (int k = 0; k < 48; ++k) acc += sm.cat3[k] * fcw[k];
        sm.contents[i * 16 + j] = acc;
    }
    __syncthreads();

    // ================= L0: 144 -> 64, 4-way split-K =================
    {
        const int q = t >> 6;
        float acc = 0.f;
        #pragma unroll
        for (int k = 0; k < 36; ++k) acc += sm.xa[q * 36 + k] * w0r[k];
        sm.partial[t] = acc;
    }
    __syncthreads();
    if (t < 64) {
        float acc = b0r + sm.partial[t] + sm.partial[64 + t] + sm.partial[128 + t] + sm.partial[192 + t];
        sm.xb[t] = lrelu(acc);
    } else if (t < 80) {
        sm.xb[t] = sm.contents[16 + (t - 64)];    // c1 -> xb[64..80)
    }
    __syncthreads();

    // ================= L1: 80 -> 32, 8-way split-K =================
    {
        const int q = t >> 5;
        float acc = 0.f;
        #pragma unroll
        for (int k = 0; k < 10; ++k) acc += sm.xb[q * 10 + k] * w1r[k];
        sm.partial[t] = acc;
    }
    __syncthreads();
    if (t < 32) {
        float acc = b1r;
        #pragma unroll
        for (int q = 0; q < 8; ++q) acc += sm.partial[q * 32 + t];
        sm.xa[t] = lrelu(acc);
    } else if (t < 48) {
        sm.xa[t] = sm.contents[32 + (t - 32)];    // c2 -> xa[32..48)
    }
    __syncthreads();

    // ================= L2: 48 -> 16, 16-way split-K =================
    {
        const int q = t >> 4;
        float acc = 0.f;
        #pragma unroll
        for (int k = 0; k < 3; ++k) acc += sm.xa[q * 3 + k] * w2r[k];
        sm.partial[t] = acc;
    }
    __syncthreads();
    if (t < 16) {
        float acc = b2r;
        #pragma unroll
        for (int q = 0; q < 16; ++q) acc += sm.partial[q * 16 + t];
        sm.xb[t] = lrelu(acc);
    } else if (t < 32) {
        sm.xb[t] = sm.contents[48 + (t - 16)];    // c3 -> xb[16..32)
    }
    __syncthreads();

    // ================= L3: 32 -> 8, 32-way split-K =================
    {
        const int q = t >> 3;
        sm.partial[t] = sm.xb[q] * w3r;
    }
    __syncthreads();
    if (t < 8) {
        float acc = b3r;
        #pragma unroll
        for (int q = 0; q < 32; ++q) acc += sm.partial[q * 8 + t];
        sm.xa[t] = lrelu(acc);
    }
    __syncthreads();

    // ================= L4: 24 -> 1, redundant per-thread =================
    // W4/b4 addresses are thread-invariant -> scalar loads; xa/contents reads
    // are uniform LDS broadcasts. No partials, no further barriers.
    float res;
    {
        float acc = LDF<F>(a.bias[4], 0);
        #pragma unroll
        for (int k = 0; k < 8; ++k)  acc += sm.xa[k] * LDF<F>(a.W[4], k);
        #pragma unroll
        for (int k = 0; k < 16; ++k) acc += sm.contents[64 + k] * LDF<F>(a.W[4], 8 + k);
        res = acc;
    }

    // ================= fill this block's 32 KB slice =================
    const float4 val = make_float4(res, res, res, res);
    float4* __restrict__ o = reinterpret_cast<float4*>(out) + (size_t)b * 16384 + slice * 2048;
    #pragma unroll
    for (int k = 0; k < 8; ++k) o[k * 256 + t] = val;
}

__global__ __launch_bounds__(256) void fgl_fused_kernel(ChainArgs a, float* __restrict__ out)
{
    const int b = blockIdx.x >> 3;       // batch
    const int slice = blockIdx.x & 7;    // 1/8 of the batch's output
    const int t = threadIdx.x;

    __shared__ Smem sm;
    __shared__ int FI_s;

    // dtype sniff (validated rounds 3-6):
    //  F: any of z's first 32 words with bf16-exponent(low half) >= 0x89 -> f32.
    //  I: contrasts values 0..199; int64 => 32 high words all zero.
    if (t < 64) {
        bool fcond = false, icond = false;
        if (t < 32) {
            unsigned int wz = ((const unsigned int*)a.z)[t];
            fcond = ((wz >> 7) & 0xFF) >= 0x89;
            icond = (((const unsigned int*)a.contrasts)[2 * t + 1] != 0u);
        }
        unsigned long long bf = __ballot(fcond);
        unsigned long long bi = __ballot(icond);
        if (t == 0) FI_s = (bf ? 1 : 0) | ((bi == 0ull) ? 2 : 0);
    }
    __syncthreads();
    const int FI = FI_s;

    if (FI == 1)      chain_fill<1, 0>(a, out, b, slice, t, sm);
    else if (FI == 3) chain_fill<1, 1>(a, out, b, slice, t, sm);
    else if (FI == 0) chain_fill<0, 0>(a, out, b, slice, t, sm);
    else              chain_fill<0, 1>(a, out, b, slice, t, sm);
}

extern "C" void kernel_launch(void* const* d_in, const int* in_sizes, int n_in,
                              void* d_out, int out_size, void* d_ws, size_t ws_size,
                              hipStream_t stream) {
    ChainArgs a;
    a.z = d_in[0];
    a.studies = d_in[1];
    a.tasks = d_in[2];
    a.contrasts = d_in[3];
    // d_in[4..8] = p0..p4 — mathematically irrelevant
    a.emb_s_v = d_in[9];  a.emb_s_g = d_in[10];
    a.emb_t_v = d_in[11]; a.emb_t_g = d_in[12];
    a.emb_c_v = d_in[13]; a.emb_c_g = d_in[14];
    for (int i = 0; i < 5; ++i) {
        a.fc_w[i] = d_in[15 + 2 * i];
        a.fc_b[i] = d_in[16 + 2 * i];
        a.W[i]    = d_in[25 + 2 * i];
        a.bias[i] = d_in[26 + 2 * i];
    }
    // 512 blocks: 64 batches x 8 slices; each block = chain + 32 KB fill.
    fgl_fused_kernel<<<512, 256, 0, stream>>>(a, (float*)d_out);
}